// Round 13
// baseline (239.209 us; speedup 1.0000x reference)
//
#include <hip/hip_runtime.h>

typedef __attribute__((ext_vector_type(8))) short bf16x8;
typedef __attribute__((ext_vector_type(4))) float f32x4;
typedef __attribute__((ext_vector_type(2))) uint u32x2;
typedef __attribute__((ext_vector_type(4))) uint u32x4;

static inline size_t align256(size_t x) { return (x + 255) & ~size_t(255); }

__device__ inline ushort f2bf(float f) {
  uint u = __float_as_uint(f);
  return (ushort)((u + 0x7FFFu + ((u >> 16) & 1u)) >> 16);  // RNE
}
__device__ inline float bf2f(ushort h) { return __uint_as_float(((uint)h) << 16); }

// ---- fp8 e4m3 codec (HW cvt if available; self-consistent fallback) ----

__device__ inline uint fp8x4_enc(float a0, float a1, float a2, float a3) {
#if __has_builtin(__builtin_amdgcn_cvt_pk_fp8_f32)
  int v = 0;
  v = __builtin_amdgcn_cvt_pk_fp8_f32(a0, a1, v, false);
  v = __builtin_amdgcn_cvt_pk_fp8_f32(a2, a3, v, true);
  return (uint)v;
#else
  float a[4] = {a0, a1, a2, a3};
  uint r = 0;
#pragma unroll
  for (int k = 0; k < 4; ++k) {
    uint u = __float_as_uint(a[k]);
    uint s = (u >> 24) & 0x80u;
    uint au = u & 0x7FFFFFFFu;
    uint b;
    if (au < 0x3C800000u) {
      b = s;
    } else {
      uint rr = au + 0x7FFFFu + ((au >> 20) & 1u);
      uint e = (rr >> 23) - 120u;
      uint m = (rr >> 20) & 7u;
      b = s | (e << 3) | m;
    }
    r |= b << (8 * k);
  }
  return r;
#endif
}

__device__ inline f32x4 fp8x4_dec(uint u) {
  f32x4 r;
#if __has_builtin(__builtin_amdgcn_cvt_pk_f32_fp8)
  auto lo = __builtin_amdgcn_cvt_pk_f32_fp8((int)u, false);
  auto hi = __builtin_amdgcn_cvt_pk_f32_fp8((int)u, true);
  r[0] = lo[0]; r[1] = lo[1]; r[2] = hi[0]; r[3] = hi[1];
#else
#pragma unroll
  for (int k = 0; k < 4; ++k) {
    uint b = (u >> (8 * k)) & 0xFFu;
    uint f = ((b & 0x80u) << 24) | (((b & 0x7Fu) + (120u << 3)) << 20);
    r[k] = (b & 0x7Fu) ? __uint_as_float(f) : 0.f;
  }
#endif
  return r;
}

// edge record: u = (col<<15) | (bf16(w) sans sign, 15 bits)
__device__ inline float ew_dec(uint u) { return __uint_as_float((u & 0x7FFFu) << 16); }

#define BW_SHIFT 7            // 128 nodes per bucket
#define NBUCK_MAX 1024
#define NCHUNK 256
#define PREP_BLOCKS 96        // 3*16384/512

// ---- A: chunk-aligned bucket hist (persisted) + W prep + tail bucket-scan ----

__global__ __launch_bounds__(512) void build_a_kernel(
    const int* __restrict__ row, int* __restrict__ bcnt,
    int* __restrict__ chunk_hist, int E, int chunk,
    const float* __restrict__ W0, const float* __restrict__ W1,
    const float* __restrict__ W2, ushort* __restrict__ Wt,
    int* __restrict__ done, int* __restrict__ boff, int* __restrict__ gcur,
    int* __restrict__ offp, int n) {
  __shared__ int h[NBUCK_MAX];
  int bid = blockIdx.x;
  int t = threadIdx.x;
  if (bid < NCHUNK) {
    for (int i = t; i < NBUCK_MAX; i += 512) h[i] = 0;
    __syncthreads();
    int c0 = bid * chunk, c1 = min(c0 + chunk, E);
    for (int i = c0 + t; i < c1; i += 512)
      atomicAdd(&h[row[i] >> BW_SHIFT], 1);
    __syncthreads();
    for (int i = t; i < NBUCK_MAX; i += 512) {
      int c = h[i];
      chunk_hist[bid * NBUCK_MAX + i] = c;
      if (c) atomicAdd(&bcnt[i], c);
    }
  } else {
    int i = (bid - NCHUNK) * 512 + t;  // < 3*16384
    int mat = i >> 14, r = i & 16383;
    int k = r >> 7, c = r & 127;
    const float* W = (mat == 0) ? W0 : (mat == 1) ? W1 : W2;
    Wt[mat * 16384 + c * 128 + k] = f2bf(W[k * 128 + c]);
  }
  __shared__ int ticket;
  __syncthreads();
  if (t == 0) {
    __threadfence();
    ticket = atomicAdd(done, 1);
  }
  __syncthreads();
  if (ticket == (int)gridDim.x - 1) {
    __threadfence();
    int v0 = bcnt[2 * t], v1 = bcnt[2 * t + 1];
    int pair = v0 + v1;
    h[t] = pair;
    __syncthreads();
    for (int o = 1; o < 512; o <<= 1) {
      int a = (t >= o) ? h[t - o] : 0;
      __syncthreads();
      h[t] += a;
      __syncthreads();
    }
    int excl = h[t] - pair;
    boff[2 * t] = excl;          gcur[2 * t] = excl;
    boff[2 * t + 1] = excl + v0; gcur[2 * t + 1] = excl + v0;
    if (t == 511) boff[NBUCK_MAX] = E;
    if (t == 0) offp[n] = E;
  }
}

// ---- B: binned scatter + x -> fp8 conversion (independent roles) ----

__global__ __launch_bounds__(512) void scatter_x8_kernel(
    const int* __restrict__ row, const int* __restrict__ col,
    const float* __restrict__ w, int* __restrict__ gcur,
    const int* __restrict__ chunk_hist, int2* __restrict__ es_tmp,
    int E, int chunk,
    const float* __restrict__ x, unsigned char* __restrict__ x8, int ne8) {
  int bid = blockIdx.x;
  int t = threadIdx.x;
  if (bid < NCHUNK) {
    __shared__ int lbase[NBUCK_MAX];
    __shared__ int lh[NBUCK_MAX];
    for (int i = t; i < NBUCK_MAX; i += 512) {
      int c = chunk_hist[bid * NBUCK_MAX + i];
      lbase[i] = c ? atomicAdd(&gcur[i], c) : 0;
      lh[i] = 0;
    }
    __syncthreads();
    int c0 = bid * chunk, c1 = min(c0 + chunk, E);
    for (int i = c0 + t; i < c1; i += 512) {
      int r = row[i];
      int b = r >> BW_SHIFT;
      int pos = lbase[b] + atomicAdd(&lh[b], 1);
      es_tmp[pos] = make_int2(((r & 127) << 17) | col[i], __float_as_int(w[i]));
    }
    return;
  }
  int i = (bid - NCHUNK) * 512 + t;
  if (i < ne8) {
    size_t base = (size_t)i * 8;
    float4 a = *(const float4*)(x + base);
    float4 b = *(const float4*)(x + base + 4);
    u32x2 v;
    v.x = fp8x4_enc(a.x, a.y, a.z, a.w);
    v.y = fp8x4_enc(b.x, b.y, b.z, b.w);
    *(u32x2*)(x8 + base) = v;
  }
}

// ---- C: per-bucket node sort (4-B records, + s1 rowsums) + GEMM0 role ----

__global__ __launch_bounds__(256) void sort_gemm0_kernel(
    const int2* __restrict__ es_tmp, const int* __restrict__ boff,
    uint* __restrict__ es, int* __restrict__ offp, float* __restrict__ s1,
    int ng,
    const float* __restrict__ x, const ushort* __restrict__ Wt,
    const float* __restrict__ b0, float* __restrict__ out0, int n) {
  int t = threadIdx.x;
  if ((int)blockIdx.x >= ng) {
    // ---------- sort role (+ s1) ----------
    __shared__ int lh[128];
    __shared__ int lex[128];
    __shared__ float sld[128];
    int b = (int)blockIdx.x - ng;
    int base = boff[b], cnt = boff[b + 1] - base;
    if (t < 128) { lh[t] = 0; sld[t] = 0.f; }
    __syncthreads();
    for (int i = t; i < cnt; i += 256)
      atomicAdd(&lh[(es_tmp[base + i].x >> 17) & 127], 1);
    __syncthreads();
    if (t < 128) lex[t] = lh[t];
    __syncthreads();
    for (int o = 1; o < 128; o <<= 1) {
      int a = (t >= o && t < 128) ? lex[t - o] : 0;
      __syncthreads();
      if (t < 128) lex[t] += a;
      __syncthreads();
    }
    int node = (b << BW_SHIFT) + t;
    if (t < 128) {
      int excl = lex[t] - lh[t];
      if (node < n) offp[node] = base + excl;
      lh[t] = excl;  // cursor
    }
    __syncthreads();
    for (int i = t; i < cnt; i += 256) {
      int2 ed = es_tmp[base + i];
      int nl = (ed.x >> 17) & 127;
      int pos = base + atomicAdd(&lh[nl], 1);
      float wv = __int_as_float(ed.y);
      atomicAdd(&sld[nl], wv);
      uint wb = (uint)f2bf(wv) & 0x7FFFu;
      es[pos] = ((uint)(ed.x & 0x1FFFF) << 15) | wb;
    }
    __syncthreads();
    if (t < 128 && node < n) s1[node] = sld[t];
    return;
  }
  // ---------- GEMM0 role: out0 = bf16(x) @ W0 + b0 (exact fp32 x input) ----------
  int w = t >> 6;
  int l = t & 63;
  int lr = l & 15;
  int lg = l >> 4;
  int rows0 = (int)blockIdx.x * 256 + w * 64;

  bf16x8 xf[4][4];
#pragma unroll
  for (int rt = 0; rt < 4; ++rt) {
    int row = rows0 + rt * 16 + lr;
    bool ok = row < n;
    const float* base = x + (size_t)row * 128;
#pragma unroll
    for (int kc = 0; kc < 4; ++kc) {
      float4 a = ok ? *(const float4*)(base + kc * 32 + lg * 8) : make_float4(0, 0, 0, 0);
      float4 c = ok ? *(const float4*)(base + kc * 32 + lg * 8 + 4) : make_float4(0, 0, 0, 0);
      bf16x8 f;
      f[0] = (short)f2bf(a.x); f[1] = (short)f2bf(a.y);
      f[2] = (short)f2bf(a.z); f[3] = (short)f2bf(a.w);
      f[4] = (short)f2bf(c.x); f[5] = (short)f2bf(c.y);
      f[6] = (short)f2bf(c.z); f[7] = (short)f2bf(c.w);
      xf[rt][kc] = f;
    }
  }
#pragma unroll 1
  for (int ct = 0; ct < 8; ++ct) {
    bf16x8 wf[4];
#pragma unroll
    for (int kc = 0; kc < 4; ++kc)
      wf[kc] = *(const bf16x8*)(Wt + (ct * 16 + lr) * 128 + kc * 32 + lg * 8);
    float4 bb = *(const float4*)(b0 + ct * 16 + lg * 4);
    f32x4 acc[4];
#pragma unroll
    for (int rt = 0; rt < 4; ++rt) {
      acc[rt][0] = bb.x; acc[rt][1] = bb.y; acc[rt][2] = bb.z; acc[rt][3] = bb.w;
    }
#pragma unroll
    for (int kc = 0; kc < 4; ++kc)
#pragma unroll
      for (int rt = 0; rt < 4; ++rt)
        acc[rt] = __builtin_amdgcn_mfma_f32_16x16x32_bf16(wf[kc], xf[rt][kc], acc[rt], 0, 0, 0);
#pragma unroll
    for (int rt = 0; rt < 4; ++rt) {
      int row = rows0 + rt * 16 + lr;
      if (row >= n) continue;
      int colc = ct * 16 + lg * 4;
      __builtin_nontemporal_store(acc[rt], (f32x4*)(out0 + (size_t)row * 384 + colc));
    }
  }
}

// ---- shared GEMM-from-p1 (bf16 input, bias = s1[row]*b[col]) ----

template <bool F32OUT>
__device__ inline void gemm_p1(const ushort* __restrict__ p1,
                               const ushort* __restrict__ Wm,
                               const float* __restrict__ bias,
                               const float* __restrict__ s1,
                               int gb, int n, int t,
                               float* __restrict__ of,    // stride 384, NT
                               ushort* __restrict__ oh) { // stride 128, cached
  int w = t >> 6, l = t & 63, lr = l & 15, lg = l >> 4;
  int rows0 = gb * 256 + w * 64;
  bf16x8 zer;
#pragma unroll
  for (int q = 0; q < 8; ++q) zer[q] = 0;
  bf16x8 xf[4][4];
  float sv[4];
#pragma unroll
  for (int rt = 0; rt < 4; ++rt) {
    int row = rows0 + rt * 16 + lr;
    bool ok = row < n;
    sv[rt] = ok ? s1[row] : 0.f;
    const ushort* base = p1 + (size_t)row * 128;
#pragma unroll
    for (int kc = 0; kc < 4; ++kc)
      xf[rt][kc] = ok ? *(const bf16x8*)(base + kc * 32 + lg * 8) : zer;
  }
#pragma unroll 1
  for (int ct = 0; ct < 8; ++ct) {
    bf16x8 wf[4];
#pragma unroll
    for (int kc = 0; kc < 4; ++kc)
      wf[kc] = *(const bf16x8*)(Wm + (ct * 16 + lr) * 128 + kc * 32 + lg * 8);
    float4 bb = *(const float4*)(bias + ct * 16 + lg * 4);
    f32x4 acc[4];
#pragma unroll
    for (int rt = 0; rt < 4; ++rt) {
      acc[rt][0] = sv[rt] * bb.x; acc[rt][1] = sv[rt] * bb.y;
      acc[rt][2] = sv[rt] * bb.z; acc[rt][3] = sv[rt] * bb.w;
    }
#pragma unroll
    for (int kc = 0; kc < 4; ++kc)
#pragma unroll
      for (int rt = 0; rt < 4; ++rt)
        acc[rt] = __builtin_amdgcn_mfma_f32_16x16x32_bf16(wf[kc], xf[rt][kc], acc[rt], 0, 0, 0);
#pragma unroll
    for (int rt = 0; rt < 4; ++rt) {
      int row = rows0 + rt * 16 + lr;
      if (row >= n) continue;
      int colc = ct * 16 + lg * 4;
      if (F32OUT) {
        __builtin_nontemporal_store(acc[rt], (f32x4*)(of + (size_t)row * 384 + colc));
      } else {
        u32x2 hh;
        hh.x = (uint)f2bf(acc[rt][0]) | ((uint)f2bf(acc[rt][1]) << 16);
        hh.y = (uint)f2bf(acc[rt][2]) | ((uint)f2bf(acc[rt][3]) << 16);
        *(u32x2*)(oh + (size_t)row * 128 + colc) = hh;
      }
    }
  }
}

// ---- D: spmm1 p1 = A * x8 (fp8 gather, half-wave per node, 4 B/lane) ----

__global__ __launch_bounds__(256) void spmm1_kernel(
    const unsigned char* __restrict__ x8,
    ushort* __restrict__ p1,       // bf16, stride 128 (re-read -> cached)
    const int* __restrict__ off, const uint* __restrict__ es, int n) {
  int node = blockIdx.x * 8 + ((threadIdx.x >> 6) << 1) + ((threadIdx.x & 63) >> 5);
  if (node >= n) return;
  int h = threadIdx.x & 31;
  int s = off[node], e = off[node + 1];
  float a0 = 0.f, a1 = 0.f, a2 = 0.f, a3 = 0.f;
  int i = s;
  for (; i + 8 <= e; i += 8) {
    uint u[8];
    float w[8];
#pragma unroll
    for (int j = 0; j < 8; ++j) {
      uint ed = es[i + j];
      w[j] = ew_dec(ed);
      u[j] = *(const uint*)(x8 + (size_t)(ed >> 15) * 128 + h * 4);
    }
#pragma unroll
    for (int j = 0; j < 8; ++j) {
      f32x4 p = fp8x4_dec(u[j]);
      a0 += w[j] * p[0]; a1 += w[j] * p[1];
      a2 += w[j] * p[2]; a3 += w[j] * p[3];
    }
  }
  for (; i < e; ++i) {
    uint ed = es[i];
    float w = ew_dec(ed);
    f32x4 p = fp8x4_dec(*(const uint*)(x8 + (size_t)(ed >> 15) * 128 + h * 4));
    a0 += w * p[0]; a1 += w * p[1]; a2 += w * p[2]; a3 += w * p[3];
  }
  u32x2 z;
  z.x = (uint)f2bf(a0) | ((uint)f2bf(a1) << 16);
  z.y = (uint)f2bf(a2) | ((uint)f2bf(a3) << 16);
  *(u32x2*)(p1 + (size_t)node * 128 + h * 4) = z;
}

// ---- Gz: z2 = p1@W2 + s1*b2 (bf16)  ||  out1 = p1@W1 + s1*b1 (fp32 NT) ----

__global__ __launch_bounds__(256) void gemm_z_kernel(
    const ushort* __restrict__ p1, const ushort* __restrict__ Wt,
    const float* __restrict__ b1, const float* __restrict__ b2,
    const float* __restrict__ s1,
    float* __restrict__ o1, ushort* __restrict__ z2, int ng, int n) {
  if ((int)blockIdx.x < ng)
    gemm_p1<false>(p1, Wt + 2 * 16384, b2, s1, blockIdx.x, n, threadIdx.x,
                   nullptr, z2);
  else
    gemm_p1<true>(p1, Wt + 16384, b1, s1, (int)blockIdx.x - ng, n, threadIdx.x,
                  o1, nullptr);
}

// ---- E: spmm2 out2 = A * z2 (bf16 gather, half-wave per node, 8 B/lane) ----

__global__ __launch_bounds__(256) void spmm2_kernel(
    const ushort* __restrict__ z2,
    float* __restrict__ o2,        // d_out + 256, stride 384
    const int* __restrict__ off, const uint* __restrict__ es, int n) {
  int node = blockIdx.x * 8 + ((threadIdx.x >> 6) << 1) + ((threadIdx.x & 63) >> 5);
  if (node >= n) return;
  int h = threadIdx.x & 31;
  int s = off[node], e = off[node + 1];
  float a0 = 0.f, a1 = 0.f, a2 = 0.f, a3 = 0.f;
  int i = s;
  for (; i + 4 <= e; i += 4) {
    u32x2 u[4];
    float w[4];
#pragma unroll
    for (int j = 0; j < 4; ++j) {
      uint ed = es[i + j];
      w[j] = ew_dec(ed);
      u[j] = *(const u32x2*)(z2 + (size_t)(ed >> 15) * 128 + h * 4);
    }
#pragma unroll
    for (int j = 0; j < 4; ++j) {
      a0 += w[j] * bf2f((ushort)u[j].x); a1 += w[j] * bf2f((ushort)(u[j].x >> 16));
      a2 += w[j] * bf2f((ushort)u[j].y); a3 += w[j] * bf2f((ushort)(u[j].y >> 16));
    }
  }
  for (; i < e; ++i) {
    uint ed = es[i];
    float w = ew_dec(ed);
    u32x2 u = *(const u32x2*)(z2 + (size_t)(ed >> 15) * 128 + h * 4);
    a0 += w * bf2f((ushort)u.x); a1 += w * bf2f((ushort)(u.x >> 16));
    a2 += w * bf2f((ushort)u.y); a3 += w * bf2f((ushort)(u.y >> 16));
  }
  f32x4 v; v[0] = a0; v[1] = a1; v[2] = a2; v[3] = a3;
  __builtin_nontemporal_store(v, (f32x4*)(o2 + (size_t)node * 384 + h * 4));
}

// ---------------- launch ----------------

extern "C" void kernel_launch(void* const* d_in, const int* in_sizes, int n_in,
                              void* d_out, int out_size, void* d_ws, size_t ws_size,
                              hipStream_t stream) {
  const float* x   = (const float*)d_in[0];
  const int*   row = (const int*)d_in[1];
  const int*   col = (const int*)d_in[2];
  const float* ew  = (const float*)d_in[3];
  const float* W0  = (const float*)d_in[4];
  const float* b0  = (const float*)d_in[5];
  const float* W1  = (const float*)d_in[6];
  const float* b1  = (const float*)d_in[7];
  const float* W2  = (const float*)d_in[8];
  const float* b2  = (const float*)d_in[9];
  float* out = (float*)d_out;

  int n = in_sizes[0] / 128;
  int E = in_sizes[1];

  char* p = (char*)d_ws;
  size_t o = 0;
  unsigned char* x8 = (unsigned char*)(p + o); o = align256(o + (size_t)n * 128);
  ushort* p1  = (ushort*)(p + o); o = align256(o + (size_t)n * 128 * 2);
  ushort* z2  = (ushort*)(p + o); o = align256(o + (size_t)n * 128 * 2);
  ushort* Wt  = (ushort*)(p + o); o = align256(o + (size_t)3 * 16384 * 2);
  float* s1   = (float*)(p + o);  o = align256(o + (size_t)n * 4);
  int* bcnt   = (int*)(p + o);    o = align256(o + (size_t)(NBUCK_MAX + 1) * 4);
  int* done   = bcnt + NBUCK_MAX;  // zeroed together with bcnt
  int* boff   = (int*)(p + o);    o = align256(o + (size_t)(NBUCK_MAX + 1) * 4);
  int* gcur   = (int*)(p + o);    o = align256(o + (size_t)NBUCK_MAX * 4);
  int* offp   = (int*)(p + o);    o = align256(o + ((size_t)n + 1) * 4);
  int* chist  = (int*)(p + o);    o = align256(o + (size_t)NCHUNK * NBUCK_MAX * 4);
  int2* es_t  = (int2*)(p + o);   o = align256(o + (size_t)E * 8);
  uint* es    = (uint*)(p + o);   o = align256(o + (size_t)E * 4);
  (void)ws_size; (void)n_in; (void)out_size;

  int nbuck = (n + 127) >> 7;
  int ng = (n + 255) / 256;
  int nsp = (n + 7) / 8;
  int chunk = (E + NCHUNK - 1) / NCHUNK;
  int ne8 = n * 128 / 8;
  int xb = (ne8 + 511) / 512;

  hipMemsetAsync(bcnt, 0, (size_t)(NBUCK_MAX + 1) * 4, stream);

  // A: chunk hist (persisted) + W prep, tail-scan by last block
  build_a_kernel<<<NCHUNK + PREP_BLOCKS, 512, 0, stream>>>(
      row, bcnt, chist, E, chunk, W0, W1, W2, Wt, done, boff, gcur, offp, n);

  // B: binned scatter + x->fp8
  scatter_x8_kernel<<<NCHUNK + xb, 512, 0, stream>>>(
      row, col, ew, gcur, chist, es_t, E, chunk, x, x8, ne8);

  // C: node sort (+s1) + GEMM0 (out cols 0..127)
  sort_gemm0_kernel<<<ng + nbuck, 256, 0, stream>>>(
      es_t, boff, es, offp, s1, ng, x, Wt, b0, out, n);

  // D: p1 = A * x8
  spmm1_kernel<<<nsp, 256, 0, stream>>>(x8, p1, offp, es, n);

  // Gz: z2 = p1@W2 + s1 b2 (bf16) || out1 = p1@W1 + s1 b1 -> out[:,128:256]
  gemm_z_kernel<<<2 * ng, 256, 0, stream>>>(p1, Wt, b1, b2, s1,
                                            out + 128, z2, ng, n);

  // E: out2 = A * z2 -> out[:,256:384]
  spmm2_kernel<<<nsp, 256, 0, stream>>>(z2, out + 256, offp, es, n);
}

// Round 14
// 224.647 us; speedup vs baseline: 1.0648x; 1.0648x over previous
//
#include <hip/hip_runtime.h>

typedef __attribute__((ext_vector_type(8))) short bf16x8;
typedef __attribute__((ext_vector_type(4))) float f32x4;
typedef __attribute__((ext_vector_type(2))) float f32x2;
typedef __attribute__((ext_vector_type(2))) uint u32x2;

static inline size_t align256(size_t x) { return (x + 255) & ~size_t(255); }

__device__ inline ushort f2bf(float f) {
  uint u = __float_as_uint(f);
  return (ushort)((u + 0x7FFFu + ((u >> 16) & 1u)) >> 16);  // RNE
}
__device__ inline float bf2f(ushort h) { return __uint_as_float(((uint)h) << 16); }

// ---- fp8 e4m3 codec (HW cvt if available; self-consistent fallback) ----

__device__ inline uint fp8x4_enc(float a0, float a1, float a2, float a3) {
#if __has_builtin(__builtin_amdgcn_cvt_pk_fp8_f32)
  int v = 0;
  v = __builtin_amdgcn_cvt_pk_fp8_f32(a0, a1, v, false);
  v = __builtin_amdgcn_cvt_pk_fp8_f32(a2, a3, v, true);
  return (uint)v;
#else
  float a[4] = {a0, a1, a2, a3};
  uint r = 0;
#pragma unroll
  for (int k = 0; k < 4; ++k) {
    uint u = __float_as_uint(a[k]);
    uint s = (u >> 24) & 0x80u;
    uint au = u & 0x7FFFFFFFu;
    uint b;
    if (au < 0x3C800000u) {
      b = s;
    } else {
      uint rr = au + 0x7FFFFu + ((au >> 20) & 1u);
      uint e = (rr >> 23) - 120u;
      uint m = (rr >> 20) & 7u;
      b = s | (e << 3) | m;
    }
    r |= b << (8 * k);
  }
  return r;
#endif
}

__device__ inline f32x4 fp8x4_dec(uint u) {
  f32x4 r;
#if __has_builtin(__builtin_amdgcn_cvt_pk_f32_fp8)
  auto lo = __builtin_amdgcn_cvt_pk_f32_fp8((int)u, false);
  auto hi = __builtin_amdgcn_cvt_pk_f32_fp8((int)u, true);
  r[0] = lo[0]; r[1] = lo[1]; r[2] = hi[0]; r[3] = hi[1];
#else
#pragma unroll
  for (int k = 0; k < 4; ++k) {
    uint b = (u >> (8 * k)) & 0xFFu;
    uint f = ((b & 0x80u) << 24) | (((b & 0x7Fu) + (120u << 3)) << 20);
    r[k] = (b & 0x7Fu) ? __uint_as_float(f) : 0.f;
  }
#endif
  return r;
}

// edge record: u = (col<<15) | (bf16(w) sans sign, 15 bits)
__device__ inline float ew_dec(uint u) { return __uint_as_float((u & 0x7FFFu) << 16); }

#define BW_SHIFT 7            // 128 nodes per bucket
#define NBUCK_MAX 1024
#define NCHUNK 256
#define PREP_BLOCKS 96        // 3*16384/512

// ---- A: chunk-aligned bucket hist (persisted) + W prep + tail bucket-scan ----

__global__ __launch_bounds__(512) void build_a_kernel(
    const int* __restrict__ row, int* __restrict__ bcnt,
    int* __restrict__ chunk_hist, int E, int chunk,
    const float* __restrict__ W0, const float* __restrict__ W1,
    const float* __restrict__ W2, ushort* __restrict__ Wt,
    int* __restrict__ done, int* __restrict__ boff, int* __restrict__ gcur,
    int* __restrict__ offp, int n) {
  __shared__ int h[NBUCK_MAX];
  int bid = blockIdx.x;
  int t = threadIdx.x;
  if (bid < NCHUNK) {
    for (int i = t; i < NBUCK_MAX; i += 512) h[i] = 0;
    __syncthreads();
    int c0 = bid * chunk, c1 = min(c0 + chunk, E);
    for (int i = c0 + t; i < c1; i += 512)
      atomicAdd(&h[row[i] >> BW_SHIFT], 1);
    __syncthreads();
    for (int i = t; i < NBUCK_MAX; i += 512) {
      int c = h[i];
      chunk_hist[bid * NBUCK_MAX + i] = c;
      if (c) atomicAdd(&bcnt[i], c);
    }
  } else {
    int i = (bid - NCHUNK) * 512 + t;  // < 3*16384
    int mat = i >> 14, r = i & 16383;
    int k = r >> 7, c = r & 127;
    const float* W = (mat == 0) ? W0 : (mat == 1) ? W1 : W2;
    Wt[mat * 16384 + c * 128 + k] = f2bf(W[k * 128 + c]);
  }
  __shared__ int ticket;
  __syncthreads();
  if (t == 0) {
    __threadfence();
    ticket = atomicAdd(done, 1);
  }
  __syncthreads();
  if (ticket == (int)gridDim.x - 1) {
    __threadfence();
    int v0 = bcnt[2 * t], v1 = bcnt[2 * t + 1];
    int pair = v0 + v1;
    h[t] = pair;
    __syncthreads();
    for (int o = 1; o < 512; o <<= 1) {
      int a = (t >= o) ? h[t - o] : 0;
      __syncthreads();
      h[t] += a;
      __syncthreads();
    }
    int excl = h[t] - pair;
    boff[2 * t] = excl;          gcur[2 * t] = excl;
    boff[2 * t + 1] = excl + v0; gcur[2 * t + 1] = excl + v0;
    if (t == 511) boff[NBUCK_MAX] = E;
    if (t == 0) offp[n] = E;
  }
}

// ---- B: binned scatter (reuses chunk_hist; no counting pass) ----

__global__ __launch_bounds__(512) void bin_scatter(
    const int* __restrict__ row, const int* __restrict__ col,
    const float* __restrict__ w, int* __restrict__ gcur,
    const int* __restrict__ chunk_hist, int2* __restrict__ es_tmp,
    int E, int chunk) {
  __shared__ int lbase[NBUCK_MAX];
  __shared__ int lh[NBUCK_MAX];
  int bid = blockIdx.x;
  int t = threadIdx.x;
  for (int i = t; i < NBUCK_MAX; i += 512) {
    int c = chunk_hist[bid * NBUCK_MAX + i];
    lbase[i] = c ? atomicAdd(&gcur[i], c) : 0;
    lh[i] = 0;
  }
  __syncthreads();
  int c0 = bid * chunk, c1 = min(c0 + chunk, E);
  for (int i = c0 + t; i < c1; i += 512) {
    int r = row[i];
    int b = r >> BW_SHIFT;
    int pos = lbase[b] + atomicAdd(&lh[b], 1);
    es_tmp[pos] = make_int2(((r & 127) << 17) | col[i], __float_as_int(w[i]));
  }
}

// ---- C+G fused: per-bucket node sort (4-B records) + 3x MFMA GEMM ----

__global__ __launch_bounds__(256) void sort_gemm_kernel(
    const int2* __restrict__ es_tmp, const int* __restrict__ boff,
    uint* __restrict__ es, int* __restrict__ offp, int ng,
    const float* __restrict__ x, const ushort* __restrict__ Wt,
    const float* __restrict__ b0, const float* __restrict__ b1,
    const float* __restrict__ b2,
    float* __restrict__ out0, unsigned char* __restrict__ y12, int n) {
  int t = threadIdx.x;
  if ((int)blockIdx.x >= ng) {
    // ---------- bucket_sort role ----------
    __shared__ int lh[128];
    __shared__ int lex[128];
    int b = (int)blockIdx.x - ng;
    int base = boff[b], cnt = boff[b + 1] - base;
    if (t < 128) lh[t] = 0;
    __syncthreads();
    for (int i = t; i < cnt; i += 256)
      atomicAdd(&lh[(es_tmp[base + i].x >> 17) & 127], 1);
    __syncthreads();
    if (t < 128) lex[t] = lh[t];
    __syncthreads();
    for (int o = 1; o < 128; o <<= 1) {
      int a = (t >= o && t < 128) ? lex[t - o] : 0;
      __syncthreads();
      if (t < 128) lex[t] += a;
      __syncthreads();
    }
    if (t < 128) {
      int v = lh[t];
      int excl = lex[t] - v;
      int node = (b << BW_SHIFT) + t;
      if (node < n) offp[node] = base + excl;
      lh[t] = excl;  // cursor
    }
    __syncthreads();
    for (int i = t; i < cnt; i += 256) {
      int2 ed = es_tmp[base + i];
      int nl = (ed.x >> 17) & 127;
      int pos = base + atomicAdd(&lh[nl], 1);
      uint wb = (uint)f2bf(__int_as_float(ed.y)) & 0x7FFFu;
      es[pos] = ((uint)(ed.x & 0x1FFFF) << 15) | wb;
    }
    return;
  }
  // ---------- gemm role ----------
  int w = t >> 6;
  int l = t & 63;
  int lr = l & 15;
  int lg = l >> 4;
  int rows0 = (int)blockIdx.x * 256 + w * 64;

  bf16x8 xf[4][4];
#pragma unroll
  for (int rt = 0; rt < 4; ++rt) {
    int row = rows0 + rt * 16 + lr;
    bool ok = row < n;
    const float* base = x + (size_t)row * 128;
#pragma unroll
    for (int kc = 0; kc < 4; ++kc) {
      float4 a = ok ? *(const float4*)(base + kc * 32 + lg * 8) : make_float4(0, 0, 0, 0);
      float4 c = ok ? *(const float4*)(base + kc * 32 + lg * 8 + 4) : make_float4(0, 0, 0, 0);
      bf16x8 f;
      f[0] = (short)f2bf(a.x); f[1] = (short)f2bf(a.y);
      f[2] = (short)f2bf(a.z); f[3] = (short)f2bf(a.w);
      f[4] = (short)f2bf(c.x); f[5] = (short)f2bf(c.y);
      f[6] = (short)f2bf(c.z); f[7] = (short)f2bf(c.w);
      xf[rt][kc] = f;
    }
  }

  for (int mat = 0; mat < 3; ++mat) {
    const ushort* Wm = Wt + mat * 16384;
    const float* bias = (mat == 0) ? b0 : (mat == 1) ? b1 : b2;
#pragma unroll 1
    for (int ct = 0; ct < 8; ++ct) {
      bf16x8 wf[4];
#pragma unroll
      for (int kc = 0; kc < 4; ++kc)
        wf[kc] = *(const bf16x8*)(Wm + (ct * 16 + lr) * 128 + kc * 32 + lg * 8);
      float4 bb = *(const float4*)(bias + ct * 16 + lg * 4);
      f32x4 acc[4];
#pragma unroll
      for (int rt = 0; rt < 4; ++rt) {
        acc[rt][0] = bb.x; acc[rt][1] = bb.y; acc[rt][2] = bb.z; acc[rt][3] = bb.w;
      }
#pragma unroll
      for (int kc = 0; kc < 4; ++kc)
#pragma unroll
        for (int rt = 0; rt < 4; ++rt)
          acc[rt] = __builtin_amdgcn_mfma_f32_16x16x32_bf16(wf[kc], xf[rt][kc], acc[rt], 0, 0, 0);
#pragma unroll
      for (int rt = 0; rt < 4; ++rt) {
        int row = rows0 + rt * 16 + lr;
        if (row >= n) continue;
        int col = ct * 16 + lg * 4;
        if (mat == 0) {
          __builtin_nontemporal_store(acc[rt], (f32x4*)(out0 + (size_t)row * 384 + col));
        } else {
          uint v8 = fp8x4_enc(acc[rt][0], acc[rt][1], acc[rt][2], acc[rt][3]);
          unsigned char* Y = y12 + (size_t)row * 256 + ((mat == 2) ? 128 : 0) + col;
          *(uint*)Y = v8;
        }
      }
    }
  }
}

// ---- D: SpMM dual (fp8 gather, FULL wave per node, 4 B/lane) ----
// node is wave-uniform -> off[]/es[] reads scalarize (readfirstlane);
// lane l reads y12 row bytes 4l..4l+3: l<32 -> y1 ch 4l.. (to o1 fp32),
// l>=32 -> y2 ch 4(l-32).. (to z2 bf16).

__global__ __launch_bounds__(256) void spmm_dual_kernel(
    const unsigned char* __restrict__ y12,
    float* __restrict__ o1,        // d_out + 128, stride 384
    ushort* __restrict__ z2,       // bf16, stride 128 (re-read -> cached)
    const int* __restrict__ off, const uint* __restrict__ es, int n) {
  int node = blockIdx.x * 4 + (threadIdx.x >> 6);
  if (node >= n) return;
  int l = threadIdx.x & 63;
  int s = __builtin_amdgcn_readfirstlane(off[node]);
  int e = __builtin_amdgcn_readfirstlane(off[node + 1]);
  float a0 = 0.f, a1 = 0.f, a2 = 0.f, a3 = 0.f;
  int i = s;
  for (; i + 8 <= e; i += 8) {
    uint u[8];
    float w[8];
#pragma unroll
    for (int j = 0; j < 8; ++j) {
      uint ed = es[i + j];
      w[j] = ew_dec(ed);
      u[j] = *(const uint*)(y12 + (size_t)(ed >> 15) * 256 + l * 4);
    }
#pragma unroll
    for (int j = 0; j < 8; ++j) {
      f32x4 p = fp8x4_dec(u[j]);
      a0 += w[j] * p[0]; a1 += w[j] * p[1];
      a2 += w[j] * p[2]; a3 += w[j] * p[3];
    }
  }
  for (; i < e; ++i) {
    uint ed = es[i];
    float w = ew_dec(ed);
    f32x4 p = fp8x4_dec(*(const uint*)(y12 + (size_t)(ed >> 15) * 256 + l * 4));
    a0 += w * p[0]; a1 += w * p[1]; a2 += w * p[2]; a3 += w * p[3];
  }
  if (l < 32) {
    f32x4 v; v[0] = a0; v[1] = a1; v[2] = a2; v[3] = a3;
    __builtin_nontemporal_store(v, (f32x4*)(o1 + (size_t)node * 384 + l * 4));
  } else {
    u32x2 z;
    z.x = (uint)f2bf(a0) | ((uint)f2bf(a1) << 16);
    z.y = (uint)f2bf(a2) | ((uint)f2bf(a3) << 16);
    *(u32x2*)(z2 + (size_t)node * 128 + (l - 32) * 4) = z;
  }
}

// ---- E: SpMM single (bf16 gather, FULL wave per node, 4 B/lane = 2 ch) ----

__global__ __launch_bounds__(256) void spmm_single_kernel(
    const ushort* __restrict__ z2,
    float* __restrict__ o2,        // d_out + 256, stride 384
    const int* __restrict__ off, const uint* __restrict__ es, int n) {
  int node = blockIdx.x * 4 + (threadIdx.x >> 6);
  if (node >= n) return;
  int l = threadIdx.x & 63;
  int s = __builtin_amdgcn_readfirstlane(off[node]);
  int e = __builtin_amdgcn_readfirstlane(off[node + 1]);
  float a0 = 0.f, a1 = 0.f;
  int i = s;
  for (; i + 8 <= e; i += 8) {
    uint u[8];
    float w[8];
#pragma unroll
    for (int j = 0; j < 8; ++j) {
      uint ed = es[i + j];
      w[j] = ew_dec(ed);
      u[j] = *(const uint*)(z2 + (size_t)(ed >> 15) * 128 + l * 2);
    }
#pragma unroll
    for (int j = 0; j < 8; ++j) {
      a0 += w[j] * bf2f((ushort)u[j]); a1 += w[j] * bf2f((ushort)(u[j] >> 16));
    }
  }
  for (; i < e; ++i) {
    uint ed = es[i];
    float w = ew_dec(ed);
    uint u = *(const uint*)(z2 + (size_t)(ed >> 15) * 128 + l * 2);
    a0 += w * bf2f((ushort)u); a1 += w * bf2f((ushort)(u >> 16));
  }
  f32x2 v; v.x = a0; v.y = a1;
  __builtin_nontemporal_store(v, (f32x2*)(o2 + (size_t)node * 384 + l * 2));
}

// ---------------- launch ----------------

extern "C" void kernel_launch(void* const* d_in, const int* in_sizes, int n_in,
                              void* d_out, int out_size, void* d_ws, size_t ws_size,
                              hipStream_t stream) {
  const float* x   = (const float*)d_in[0];
  const int*   row = (const int*)d_in[1];
  const int*   col = (const int*)d_in[2];
  const float* ew  = (const float*)d_in[3];
  const float* W0  = (const float*)d_in[4];
  const float* b0  = (const float*)d_in[5];
  const float* W1  = (const float*)d_in[6];
  const float* b1  = (const float*)d_in[7];
  const float* W2  = (const float*)d_in[8];
  const float* b2  = (const float*)d_in[9];
  float* out = (float*)d_out;

  int n = in_sizes[0] / 128;
  int E = in_sizes[1];

  char* p = (char*)d_ws;
  size_t o = 0;
  unsigned char* y12 = (unsigned char*)(p + o); o = align256(o + (size_t)n * 256);
  ushort* z2  = (ushort*)(p + o); o = align256(o + (size_t)n * 128 * 2);
  ushort* Wt  = (ushort*)(p + o); o = align256(o + (size_t)3 * 16384 * 2);
  int* bcnt   = (int*)(p + o);    o = align256(o + (size_t)(NBUCK_MAX + 1) * 4);
  int* done   = bcnt + NBUCK_MAX;  // zeroed together with bcnt
  int* boff   = (int*)(p + o);    o = align256(o + (size_t)(NBUCK_MAX + 1) * 4);
  int* gcur   = (int*)(p + o);    o = align256(o + (size_t)NBUCK_MAX * 4);
  int* offp   = (int*)(p + o);    o = align256(o + ((size_t)n + 1) * 4);
  int* chist  = (int*)(p + o);    o = align256(o + (size_t)NCHUNK * NBUCK_MAX * 4);
  int2* es_t  = (int2*)(p + o);   o = align256(o + (size_t)E * 8);
  uint* es    = (uint*)(p + o);   o = align256(o + (size_t)E * 4);
  (void)ws_size; (void)n_in; (void)out_size;

  int nbuck = (n + 127) >> 7;
  int ng = (n + 255) / 256;
  int chunk = (E + NCHUNK - 1) / NCHUNK;

  hipMemsetAsync(bcnt, 0, (size_t)(NBUCK_MAX + 1) * 4, stream);

  // A: chunk hist (persisted) + W prep, tail-scan by last block
  build_a_kernel<<<NCHUNK + PREP_BLOCKS, 512, 0, stream>>>(
      row, bcnt, chist, E, chunk, W0, W1, W2, Wt, done, boff, gcur, offp, n);

  // B: binned scatter (no counting pass)
  bin_scatter<<<NCHUNK, 512, 0, stream>>>(row, col, ew, gcur, chist, es_t, E, chunk);

  // C+G: per-bucket node sort (4-B records) + fused 3x GEMM
  sort_gemm_kernel<<<ng + nbuck, 256, 0, stream>>>(
      es_t, boff, es, offp, ng,
      x, Wt, b0, b1, b2, out, y12, n);

  // D: x1 -> out[:,128:256] (NT), z2 (bf16, cached) -> ws
  spmm_dual_kernel<<<(n + 3) / 4, 256, 0, stream>>>(y12, out + 128, z2,
                                                    offp, es, n);
  // E: x2 = A*z2 -> out[:,256:384] (NT)
  spmm_single_kernel<<<(n + 3) / 4, 256, 0, stream>>>(z2, out + 256,
                                                      offp, es, n);
}